// Round 3
// baseline (982.746 us; speedup 1.0000x reference)
//
#include <hip/hip_runtime.h>
#include <hip/hip_bf16.h>

typedef __attribute__((ext_vector_type(8))) short short8;
typedef __attribute__((ext_vector_type(4))) float f32x4;

#define S_LEN 2048
#define NH 16
#define NKV 8
#define HD 64
#define WIN 512
#define DMODEL 1024

// ---------------- cast X (fp32 -> bf16), vectorized ----------------
__global__ void cast_bf16_kernel(const float* __restrict__ X,
                                 __hip_bfloat16* __restrict__ Y, int n) {
    int i = (blockIdx.x * 256 + threadIdx.x) * 4;
    if (i + 3 < n) {
        float4 v = *reinterpret_cast<const float4*>(X + i);
        Y[i + 0] = __float2bfloat16(v.x);
        Y[i + 1] = __float2bfloat16(v.y);
        Y[i + 2] = __float2bfloat16(v.z);
        Y[i + 3] = __float2bfloat16(v.w);
    }
}

// ---------------- transpose + cast: W[K][N] fp32 -> WT[N][K] bf16 ----------------
__global__ void transpose_cast_kernel(const float* __restrict__ W,
                                      __hip_bfloat16* __restrict__ WT,
                                      int K, int N) {
    __shared__ float tile[32][33];
    int nx = blockIdx.x * 32 + threadIdx.x;   // n index (coalesced read)
    int k0 = blockIdx.y * 32;
#pragma unroll
    for (int r = 0; r < 4; ++r) {
        int k = k0 + threadIdx.y + r * 8;
        tile[threadIdx.y + r * 8][threadIdx.x] = W[(size_t)k * N + nx];
    }
    __syncthreads();
#pragma unroll
    for (int r = 0; r < 4; ++r) {
        int nn = blockIdx.x * 32 + threadIdx.y + r * 8;
        int kk = k0 + threadIdx.x;            // coalesced write along K
        WT[(size_t)nn * K + kk] = __float2bfloat16(tile[threadIdx.x][threadIdx.y + r * 8]);
    }
}

// ---------------- bf16 GEMM: C[M][N] = A[M][K] @ B[K][N], B given transposed ----
// block = 256 threads (4 waves); block tile 64(M) x 64(N); wave tile 16x64.
// MFMA 16x16x32 bf16. A frag: A[m=lane&15][k = quad*8+j]; B frag from BT rows.
// C/D: col = lane&15, row = quad*4 + reg.
template <bool OUT_F32>
__global__ __launch_bounds__(256) void gemm_bt_kernel(
    const __hip_bfloat16* __restrict__ A,
    const __hip_bfloat16* __restrict__ BT,
    void* __restrict__ Cout, int M, int N, int K) {
    const int lane = threadIdx.x & 63;
    const int wave = threadIdx.x >> 6;
    const int l16 = lane & 15;
    const int quad = lane >> 4;
    const int col0 = blockIdx.x * 64;
    const int row0 = blockIdx.y * 64 + wave * 16;

    f32x4 acc[4] = {{0.f, 0.f, 0.f, 0.f}, {0.f, 0.f, 0.f, 0.f},
                    {0.f, 0.f, 0.f, 0.f}, {0.f, 0.f, 0.f, 0.f}};

    const __hip_bfloat16* Ap = A + (size_t)(row0 + l16) * K + quad * 8;
    const __hip_bfloat16* Bp0 = BT + (size_t)(col0 + l16) * K + quad * 8;

    for (int k0 = 0; k0 < K; k0 += 32) {
        short8 a = *reinterpret_cast<const short8*>(Ap + k0);
#pragma unroll
        for (int t = 0; t < 4; ++t) {
            short8 b = *reinterpret_cast<const short8*>(Bp0 + (size_t)t * 16 * K + k0);
            acc[t] = __builtin_amdgcn_mfma_f32_16x16x32_bf16(a, b, acc[t], 0, 0, 0);
        }
    }

#pragma unroll
    for (int t = 0; t < 4; ++t) {
        int col = col0 + t * 16 + l16;
#pragma unroll
        for (int r = 0; r < 4; ++r) {
            int row = row0 + quad * 4 + r;
            if (OUT_F32)
                reinterpret_cast<float*>(Cout)[(size_t)row * N + col] = acc[t][r];
            else
                reinterpret_cast<__hip_bfloat16*>(Cout)[(size_t)row * N + col] =
                    __float2bfloat16(acc[t][r]);
        }
    }
}

// ---------------- RoPE in-place on fp32 buffer [rows][nheads*64] ----------------
__global__ void rope_f32_kernel(float* __restrict__ X, int nheads) {
    int idx = blockIdx.x * 256 + threadIdx.x;   // rows * nheads * 32 threads
    int d = idx & 31;
    int h = (idx >> 5) % nheads;
    int row = idx / (32 * nheads);
    int pos = row & (S_LEN - 1);                // row = b*S + s
    size_t base = (size_t)row * (nheads * 64) + h * 64 + d;
    float x1 = X[base];
    float x2 = X[base + 32];
    // inv_freq = 10000^(-d/32) = 2^(-d * log2(10000)/32)
    float inv_freq = exp2f(-(float)d * (13.287712379549449f / 32.0f));
    float ang = (float)pos * inv_freq;
    // NOTE: sincosf(x, &s, &c) has SIN first — previous rounds had them
    // swapped, producing R(pi/2 - theta) i.e. negated relative rotation.
    float c = cosf(ang);
    float s = sinf(ang);
    X[base]      = x1 * c - x2 * s;
    X[base + 32] = x2 * c + x1 * s;
}

// ---------------- sliding-window GQA attention ----------------
// grid (S/256, NH, B), block 256. One thread per query. Online softmax fp32.
// Q/K fp32; V bf16 (linear, relative-error-safe). K/V staged in 64-key LDS chunks.
__global__ __launch_bounds__(256) void attn_kernel(
    const float* __restrict__ Q,
    const float* __restrict__ Kf,
    const __hip_bfloat16* __restrict__ Vb,
    __hip_bfloat16* __restrict__ O) {
    __shared__ float4 ldsK[64][16];   // 64 keys x 64 fp32
    __shared__ uint4  ldsV[64][8];    // 64 keys x 64 bf16
    const int tx = threadIdx.x;
    const int qi = blockIdx.x * 256 + tx;
    const int h = blockIdx.y;
    const int b = blockIdx.z;
    const int kvh = h >> 1;

    const float4* qp = reinterpret_cast<const float4*>(
        Q + ((size_t)(b * S_LEN + qi) * (NH * HD) + h * HD));
    float qf[64];
#pragma unroll
    for (int t = 0; t < 16; ++t) {
        float4 v = qp[t];
        qf[4 * t + 0] = v.x; qf[4 * t + 1] = v.y;
        qf[4 * t + 2] = v.z; qf[4 * t + 3] = v.w;
    }
    float o[64];
#pragma unroll
    for (int d = 0; d < 64; ++d) o[d] = 0.f;
    float m = -1e30f, l = 0.f;

    const int kstart = (blockIdx.x >= 2) ? (blockIdx.x * 256 - WIN) : 0;
    const int kend = blockIdx.x * 256 + 256;
    const float4* Kp = reinterpret_cast<const float4*>(Kf);  // row stride 128
    const uint4*  Vp = reinterpret_cast<const uint4*>(Vb);   // row stride 64

    for (int j0 = kstart; j0 < kend; j0 += 64) {
        // stage K: 64 keys x 16 float4 = 1024 float4 -> 4 per thread
#pragma unroll
        for (int r = 0; r < 4; ++r) {
            int flat = tx + r * 256;
            int key = flat >> 4, d4 = flat & 15;
            ldsK[key][d4] = Kp[(size_t)(b * S_LEN + j0 + key) * 128 + kvh * 16 + d4];
        }
        // stage V: 64 keys x 8 uint4 = 512 uint4 -> 2 per thread
#pragma unroll
        for (int r = 0; r < 2; ++r) {
            int flat = tx + r * 256;
            int key = flat >> 3, d8 = flat & 7;
            ldsV[key][d8] = Vp[(size_t)(b * S_LEN + j0 + key) * 64 + kvh * 8 + d8];
        }
        __syncthreads();
        for (int jj = 0; jj < 64; ++jj) {
            int j = j0 + jj;
            if (j <= qi && j + WIN >= qi) {
                const float* kk = reinterpret_cast<const float*>(ldsK[jj]);
                float dot = 0.f;
#pragma unroll
                for (int d = 0; d < 64; ++d) dot += qf[d] * kk[d];
                float score = dot * 0.125f;
                if (score > m) {
                    float alpha = __expf(m - score);
                    l *= alpha;
#pragma unroll
                    for (int d = 0; d < 64; ++d) o[d] *= alpha;
                    m = score;
                }
                float p = __expf(score - m);
                l += p;
                const unsigned* vv = reinterpret_cast<const unsigned*>(ldsV[jj]);
#pragma unroll
                for (int t = 0; t < 32; ++t) {
                    unsigned u = vv[t];
                    o[2 * t]     += p * __uint_as_float(u << 16);
                    o[2 * t + 1] += p * __uint_as_float(u & 0xffff0000u);
                }
            }
        }
        __syncthreads();
    }

    float inv = 1.f / l;
    __hip_bfloat16* op = O + ((size_t)(b * S_LEN + qi) * (NH * HD) + h * HD);
#pragma unroll
    for (int d = 0; d < 64; ++d) op[d] = __float2bfloat16(o[d] * inv);
}

// ---------------- launch ----------------
extern "C" void kernel_launch(void* const* d_in, const int* in_sizes, int n_in,
                              void* d_out, int out_size, void* d_ws, size_t ws_size,
                              hipStream_t stream) {
    const float* X  = (const float*)d_in[0];
    const float* Wq = (const float*)d_in[1];
    const float* Wk = (const float*)d_in[2];
    const float* Wv = (const float*)d_in[3];
    const float* Wo = (const float*)d_in[4];
    float* out = (float*)d_out;

    const int ROWS = 2 * S_LEN;               // 4096
    char* ws = (char*)d_ws;
    size_t off = 0;
    __hip_bfloat16* Xb  = (__hip_bfloat16*)(ws + off); off += (size_t)ROWS * DMODEL * 2;      // 8 MB
    __hip_bfloat16* WqT = (__hip_bfloat16*)(ws + off); off += (size_t)DMODEL * DMODEL * 2;    // 2 MB
    __hip_bfloat16* WkT = (__hip_bfloat16*)(ws + off); off += (size_t)(NKV * HD) * DMODEL * 2;// 1 MB
    __hip_bfloat16* WvT = (__hip_bfloat16*)(ws + off); off += (size_t)(NKV * HD) * DMODEL * 2;// 1 MB
    __hip_bfloat16* WoT = (__hip_bfloat16*)(ws + off); off += (size_t)DMODEL * DMODEL * 2;    // 2 MB
    float* Qf           = (float*)(ws + off);          off += (size_t)ROWS * (NH * HD) * 4;   // 16 MB
    float* Kff          = (float*)(ws + off);          off += (size_t)ROWS * (NKV * HD) * 4;  // 8 MB
    __hip_bfloat16* Vbf = (__hip_bfloat16*)(ws + off); off += (size_t)ROWS * (NKV * HD) * 2;  // 4 MB
    __hip_bfloat16* Ob  = (__hip_bfloat16*)(ws + off); off += (size_t)ROWS * (NH * HD) * 2;   // 8 MB

    // 1. casts / transposes
    cast_bf16_kernel<<<(ROWS * DMODEL) / (256 * 4), 256, 0, stream>>>(X, Xb, ROWS * DMODEL);
    transpose_cast_kernel<<<dim3(DMODEL / 32, DMODEL / 32), dim3(32, 8), 0, stream>>>(Wq, WqT, DMODEL, DMODEL);
    transpose_cast_kernel<<<dim3((NKV * HD) / 32, DMODEL / 32), dim3(32, 8), 0, stream>>>(Wk, WkT, DMODEL, NKV * HD);
    transpose_cast_kernel<<<dim3((NKV * HD) / 32, DMODEL / 32), dim3(32, 8), 0, stream>>>(Wv, WvT, DMODEL, NKV * HD);
    transpose_cast_kernel<<<dim3(DMODEL / 32, DMODEL / 32), dim3(32, 8), 0, stream>>>(Wo, WoT, DMODEL, DMODEL);

    // 2. Q/K projections -> fp32; V projection -> bf16
    gemm_bt_kernel<true><<<dim3((NH * HD) / 64, ROWS / 64), 256, 0, stream>>>(Xb, WqT, Qf, ROWS, NH * HD, DMODEL);
    gemm_bt_kernel<true><<<dim3((NKV * HD) / 64, ROWS / 64), 256, 0, stream>>>(Xb, WkT, Kff, ROWS, NKV * HD, DMODEL);
    gemm_bt_kernel<false><<<dim3((NKV * HD) / 64, ROWS / 64), 256, 0, stream>>>(Xb, WvT, Vbf, ROWS, NKV * HD, DMODEL);

    // 3. RoPE in-place (fp32)
    rope_f32_kernel<<<(ROWS * NH * 32) / 256, 256, 0, stream>>>(Qf, NH);
    rope_f32_kernel<<<(ROWS * NKV * 32) / 256, 256, 0, stream>>>(Kff, NKV);

    // 4. sliding-window GQA attention
    attn_kernel<<<dim3(S_LEN / 256, NH, 2), 256, 0, stream>>>(Qf, Kff, Vbf, Ob);

    // 5. output projection -> fp32
    gemm_bt_kernel<true><<<dim3(DMODEL / 64, ROWS / 64), 256, 0, stream>>>(Ob, WoT, out, ROWS, DMODEL, DMODEL);
}

// Round 4
// 390.017 us; speedup vs baseline: 2.5197x; 2.5197x over previous
//
#include <hip/hip_runtime.h>
#include <hip/hip_bf16.h>

typedef __attribute__((ext_vector_type(8))) short short8;
typedef __attribute__((ext_vector_type(4))) float f32x4;

#define S_LEN 2048
#define NH 16
#define NKV 8
#define HD 64
#define WIN 512
#define DMODEL 1024

// ---------------- cast X (fp32 -> bf16), vectorized ----------------
__global__ void cast_bf16_kernel(const float* __restrict__ X,
                                 __hip_bfloat16* __restrict__ Y, int n) {
    int i = (blockIdx.x * 256 + threadIdx.x) * 4;
    if (i + 3 < n) {
        float4 v = *reinterpret_cast<const float4*>(X + i);
        Y[i + 0] = __float2bfloat16(v.x);
        Y[i + 1] = __float2bfloat16(v.y);
        Y[i + 2] = __float2bfloat16(v.z);
        Y[i + 3] = __float2bfloat16(v.w);
    }
}

// ---------------- transpose + cast: W[K][N] fp32 -> WT[N][K] bf16 ----------------
__global__ void transpose_cast_kernel(const float* __restrict__ W,
                                      __hip_bfloat16* __restrict__ WT,
                                      int K, int N) {
    __shared__ float tile[32][33];
    int nx = blockIdx.x * 32 + threadIdx.x;
    int k0 = blockIdx.y * 32;
#pragma unroll
    for (int r = 0; r < 4; ++r) {
        int k = k0 + threadIdx.y + r * 8;
        tile[threadIdx.y + r * 8][threadIdx.x] = W[(size_t)k * N + nx];
    }
    __syncthreads();
#pragma unroll
    for (int r = 0; r < 4; ++r) {
        int nn = blockIdx.x * 32 + threadIdx.y + r * 8;
        int kk = k0 + threadIdx.x;
        WT[(size_t)nn * K + kk] = __float2bfloat16(tile[threadIdx.x][threadIdx.y + r * 8]);
    }
}

// ---------------- bf16 GEMM: C[M][N] = A[M][K] @ B[K][N], B given transposed ----
// MODE 0: fp32 C.  MODE 1: bf16 C.  MODE 2: bf16 V-transposed store
//   VT[(b*NKV + col/64)*64 + col%64][s]  (attention-ready layout).
template <int MODE>
__global__ __launch_bounds__(256) void gemm_bt_kernel(
    const __hip_bfloat16* __restrict__ A,
    const __hip_bfloat16* __restrict__ BT,
    void* __restrict__ Cout, int M, int N, int K) {
    const int lane = threadIdx.x & 63;
    const int wave = threadIdx.x >> 6;
    const int l16 = lane & 15;
    const int quad = lane >> 4;
    const int col0 = blockIdx.x * 64;
    const int row0 = blockIdx.y * 64 + wave * 16;

    f32x4 acc[4] = {{0.f, 0.f, 0.f, 0.f}, {0.f, 0.f, 0.f, 0.f},
                    {0.f, 0.f, 0.f, 0.f}, {0.f, 0.f, 0.f, 0.f}};

    const __hip_bfloat16* Ap = A + (size_t)(row0 + l16) * K + quad * 8;
    const __hip_bfloat16* Bp0 = BT + (size_t)(col0 + l16) * K + quad * 8;

    for (int k0 = 0; k0 < K; k0 += 32) {
        short8 a = *reinterpret_cast<const short8*>(Ap + k0);
#pragma unroll
        for (int t = 0; t < 4; ++t) {
            short8 b = *reinterpret_cast<const short8*>(Bp0 + (size_t)t * 16 * K + k0);
            acc[t] = __builtin_amdgcn_mfma_f32_16x16x32_bf16(a, b, acc[t], 0, 0, 0);
        }
    }

#pragma unroll
    for (int t = 0; t < 4; ++t) {
        int col = col0 + t * 16 + l16;
        if (MODE == 2) {
            // V epilogue: store transposed, 4 consecutive s per lane (8B packed)
            int b = row0 >> 11;
            int srow = (row0 & (S_LEN - 1)) + quad * 4;
            alignas(8) __hip_bfloat16 hv[4];
#pragma unroll
            for (int r = 0; r < 4; ++r) hv[r] = __float2bfloat16(acc[t][r]);
            __hip_bfloat16* VTout = reinterpret_cast<__hip_bfloat16*>(Cout);
            *reinterpret_cast<ushort4*>(
                VTout + ((size_t)((b * NKV + (col >> 6)) * HD + (col & 63))) * S_LEN + srow) =
                *reinterpret_cast<ushort4*>(hv);
        } else {
#pragma unroll
            for (int r = 0; r < 4; ++r) {
                int row = row0 + quad * 4 + r;
                if (MODE == 0)
                    reinterpret_cast<float*>(Cout)[(size_t)row * N + col] = acc[t][r];
                else
                    reinterpret_cast<__hip_bfloat16*>(Cout)[(size_t)row * N + col] =
                        __float2bfloat16(acc[t][r]);
            }
        }
    }
}

// ---------------- RoPE in-place on bf16 buffer [rows][nheads*64] ----------------
__global__ void rope_bf16_kernel(__hip_bfloat16* __restrict__ X, int nheads) {
    int idx = blockIdx.x * 256 + threadIdx.x;
    int d = idx & 31;
    int hh = (idx >> 5) % nheads;
    int row = idx / (32 * nheads);
    int pos = row & (S_LEN - 1);
    size_t base = (size_t)row * (nheads * 64) + hh * 64 + d;
    float x1 = __bfloat162float(X[base]);
    float x2 = __bfloat162float(X[base + 32]);
    float inv_freq = exp2f(-(float)d * (13.287712379549449f / 32.0f));
    float ang = (float)pos * inv_freq;
    float c = cosf(ang), s = sinf(ang);
    X[base]      = __float2bfloat16(x1 * c - x2 * s);
    X[base + 32] = __float2bfloat16(x2 * c + x1 * s);
}

// ---------------- MFMA flash attention, sliding window ----------------
// grid (S/64, NH, B), 256 threads = 4 waves; wave w owns queries q0+16w..+15.
// Chunks of 64 keys. S = Q@K^T (C layout: row=query, col=key), online softmax
// with 4-step shfl_xor over l16, P via wave-private LDS round-trip, PV with
// B-frags from pre-transposed VT. LDS rows padded to 80 elems (b128-aligned,
// conflict-minimal); P writes quad-staggered (8-way -> 2-way, free).
__global__ __launch_bounds__(256) void attn_mfma_kernel(
    const __hip_bfloat16* __restrict__ Q,
    const __hip_bfloat16* __restrict__ K,
    const __hip_bfloat16* __restrict__ VT,
    __hip_bfloat16* __restrict__ O) {
    __shared__ __hip_bfloat16 ldsK[64][80];
    __shared__ __hip_bfloat16 ldsVT[64][80];
    __shared__ __hip_bfloat16 ldsP[4][16][80];
    const int tx = threadIdx.x;
    const int wave = tx >> 6;
    const int lane = tx & 63;
    const int l16 = lane & 15;
    const int quad = lane >> 4;
    const int q0 = blockIdx.x * 64;
    const int h = blockIdx.y;
    const int b = blockIdx.z;
    const int kvh = h >> 1;
    const int qrow = q0 + wave * 16;

    short8 aq0, aq1;
    {
        const __hip_bfloat16* qp =
            Q + (size_t)(b * S_LEN + qrow + l16) * (NH * HD) + h * HD + quad * 8;
        aq0 = *reinterpret_cast<const short8*>(qp);
        aq1 = *reinterpret_cast<const short8*>(qp + 32);
    }
    f32x4 acc_o[4] = {{0.f, 0.f, 0.f, 0.f}, {0.f, 0.f, 0.f, 0.f},
                      {0.f, 0.f, 0.f, 0.f}, {0.f, 0.f, 0.f, 0.f}};
    float m[4] = {-1e30f, -1e30f, -1e30f, -1e30f};
    float l[4] = {0.f, 0.f, 0.f, 0.f};

    const int kstart = (q0 >= WIN) ? (q0 - WIN) : 0;
    for (int j0 = kstart; j0 <= q0; j0 += 64) {
        // stage K[key][d] and VT[d][key] (uint4 = 8 bf16 per thread per round)
#pragma unroll
        for (int r = 0; r < 2; ++r) {
            int f = tx + r * 256;
            int a = f >> 3, e8 = f & 7;
            *reinterpret_cast<uint4*>(&ldsK[a][e8 * 8]) =
                *reinterpret_cast<const uint4*>(
                    K + (size_t)(b * S_LEN + j0 + a) * (NKV * HD) + kvh * HD + e8 * 8);
            *reinterpret_cast<uint4*>(&ldsVT[a][e8 * 8]) =
                *reinterpret_cast<const uint4*>(
                    VT + ((size_t)(b * NKV + kvh) * HD + a) * S_LEN + j0 + e8 * 8);
        }
        __syncthreads();

        // S = Q @ K^T
        f32x4 sacc[4] = {{0.f, 0.f, 0.f, 0.f}, {0.f, 0.f, 0.f, 0.f},
                         {0.f, 0.f, 0.f, 0.f}, {0.f, 0.f, 0.f, 0.f}};
#pragma unroll
        for (int t = 0; t < 4; ++t) {
            short8 bk0 = *reinterpret_cast<const short8*>(&ldsK[t * 16 + l16][quad * 8]);
            short8 bk1 = *reinterpret_cast<const short8*>(&ldsK[t * 16 + l16][32 + quad * 8]);
            sacc[t] = __builtin_amdgcn_mfma_f32_16x16x32_bf16(aq0, bk0, sacc[t], 0, 0, 0);
            sacc[t] = __builtin_amdgcn_mfma_f32_16x16x32_bf16(aq1, bk1, sacc[t], 0, 0, 0);
        }

        // scale + window mask
        float sv[4][4];
#pragma unroll
        for (int t = 0; t < 4; ++t)
#pragma unroll
            for (int r = 0; r < 4; ++r) {
                int i = qrow + quad * 4 + r;
                int j = j0 + t * 16 + l16;
                bool ok = (j <= i) && (j + WIN >= i);
                sv[t][r] = ok ? sacc[t][r] * 0.125f : -1e30f;
            }

        // online softmax per query (row = quad*4+r, cols spread over l16)
#pragma unroll
        for (int r = 0; r < 4; ++r) {
            float cm = fmaxf(fmaxf(sv[0][r], sv[1][r]), fmaxf(sv[2][r], sv[3][r]));
#pragma unroll
            for (int off = 1; off < 16; off <<= 1)
                cm = fmaxf(cm, __shfl_xor(cm, off));
            float mn = fmaxf(m[r], cm);
            float alpha = __expf(m[r] - mn);
            m[r] = mn;
            float sp = 0.f;
#pragma unroll
            for (int t = 0; t < 4; ++t) { sv[t][r] = __expf(sv[t][r] - mn); sp += sv[t][r]; }
#pragma unroll
            for (int off = 1; off < 16; off <<= 1)
                sp += __shfl_xor(sp, off);
            l[r] = l[r] * alpha + sp;
#pragma unroll
            for (int t = 0; t < 4; ++t) acc_o[t][r] *= alpha;
        }

        // P -> wave-private LDS (C layout -> A layout), quad-staggered
#pragma unroll
        for (int t = 0; t < 4; ++t) {
            int tt = (t + quad) & 3;
#pragma unroll
            for (int r = 0; r < 4; ++r)
                ldsP[wave][quad * 4 + r][tt * 16 + l16] = __float2bfloat16(sv[tt][r]);
        }

        // O += P @ V   (same-wave LDS write->read: DS ops complete in order)
#pragma unroll
        for (int ks = 0; ks < 2; ++ks) {
            short8 ap = *reinterpret_cast<const short8*>(&ldsP[wave][l16][ks * 32 + quad * 8]);
#pragma unroll
            for (int t = 0; t < 4; ++t) {
                short8 bv = *reinterpret_cast<const short8*>(
                    &ldsVT[t * 16 + l16][ks * 32 + quad * 8]);
                acc_o[t] = __builtin_amdgcn_mfma_f32_16x16x32_bf16(ap, bv, acc_o[t], 0, 0, 0);
            }
        }
        __syncthreads();
    }

#pragma unroll
    for (int r = 0; r < 4; ++r) {
        float inv = 1.f / l[r];
        size_t row = (size_t)(b * S_LEN + qrow + quad * 4 + r);
#pragma unroll
        for (int t = 0; t < 4; ++t)
            O[row * (NH * HD) + h * HD + t * 16 + l16] =
                __float2bfloat16(acc_o[t][r] * inv);
    }
}

// ---------------- launch ----------------
extern "C" void kernel_launch(void* const* d_in, const int* in_sizes, int n_in,
                              void* d_out, int out_size, void* d_ws, size_t ws_size,
                              hipStream_t stream) {
    const float* X  = (const float*)d_in[0];
    const float* Wq = (const float*)d_in[1];
    const float* Wk = (const float*)d_in[2];
    const float* Wv = (const float*)d_in[3];
    const float* Wo = (const float*)d_in[4];
    float* out = (float*)d_out;

    const int ROWS = 2 * S_LEN;               // 4096
    char* ws = (char*)d_ws;
    size_t off = 0;
    __hip_bfloat16* Xb  = (__hip_bfloat16*)(ws + off); off += (size_t)ROWS * DMODEL * 2;
    __hip_bfloat16* WqT = (__hip_bfloat16*)(ws + off); off += (size_t)DMODEL * DMODEL * 2;
    __hip_bfloat16* WkT = (__hip_bfloat16*)(ws + off); off += (size_t)(NKV * HD) * DMODEL * 2;
    __hip_bfloat16* WvT = (__hip_bfloat16*)(ws + off); off += (size_t)(NKV * HD) * DMODEL * 2;
    __hip_bfloat16* WoT = (__hip_bfloat16*)(ws + off); off += (size_t)DMODEL * DMODEL * 2;
    __hip_bfloat16* Qb  = (__hip_bfloat16*)(ws + off); off += (size_t)ROWS * (NH * HD) * 2;
    __hip_bfloat16* Kb  = (__hip_bfloat16*)(ws + off); off += (size_t)ROWS * (NKV * HD) * 2;
    __hip_bfloat16* VTg = (__hip_bfloat16*)(ws + off); off += (size_t)ROWS * (NKV * HD) * 2;
    __hip_bfloat16* Ob  = (__hip_bfloat16*)(ws + off); off += (size_t)ROWS * (NH * HD) * 2;

    // 1. casts / transposes
    cast_bf16_kernel<<<(ROWS * DMODEL) / (256 * 4), 256, 0, stream>>>(X, Xb, ROWS * DMODEL);
    transpose_cast_kernel<<<dim3(DMODEL / 32, DMODEL / 32), dim3(32, 8), 0, stream>>>(Wq, WqT, DMODEL, DMODEL);
    transpose_cast_kernel<<<dim3((NKV * HD) / 32, DMODEL / 32), dim3(32, 8), 0, stream>>>(Wk, WkT, DMODEL, NKV * HD);
    transpose_cast_kernel<<<dim3((NKV * HD) / 32, DMODEL / 32), dim3(32, 8), 0, stream>>>(Wv, WvT, DMODEL, NKV * HD);
    transpose_cast_kernel<<<dim3(DMODEL / 32, DMODEL / 32), dim3(32, 8), 0, stream>>>(Wo, WoT, DMODEL, DMODEL);

    // 2. projections: Q,K -> bf16; V -> transposed bf16 (attention-ready)
    gemm_bt_kernel<1><<<dim3((NH * HD) / 64, ROWS / 64), 256, 0, stream>>>(Xb, WqT, Qb, ROWS, NH * HD, DMODEL);
    gemm_bt_kernel<1><<<dim3((NKV * HD) / 64, ROWS / 64), 256, 0, stream>>>(Xb, WkT, Kb, ROWS, NKV * HD, DMODEL);
    gemm_bt_kernel<2><<<dim3((NKV * HD) / 64, ROWS / 64), 256, 0, stream>>>(Xb, WvT, VTg, ROWS, NKV * HD, DMODEL);

    // 3. RoPE in-place (bf16)
    rope_bf16_kernel<<<(ROWS * NH * 32) / 256, 256, 0, stream>>>(Qb, NH);
    rope_bf16_kernel<<<(ROWS * NKV * 32) / 256, 256, 0, stream>>>(Kb, NKV);

    // 4. MFMA flash attention
    attn_mfma_kernel<<<dim3(S_LEN / 64, NH, 2), 256, 0, stream>>>(Qb, Kb, VTg, Ob);

    // 5. output projection -> fp32
    gemm_bt_kernel<0><<<dim3(DMODEL / 64, ROWS / 64), 256, 0, stream>>>(Ob, WoT, out, ROWS, DMODEL, DMODEL);
}

// Round 5
// 188.144 us; speedup vs baseline: 5.2234x; 2.0730x over previous
//
#include <hip/hip_runtime.h>
#include <hip/hip_bf16.h>

typedef __attribute__((ext_vector_type(8))) short short8;
typedef __attribute__((ext_vector_type(4))) float f32x4;

#define S_LEN 2048
#define NH 16
#define NKV 8
#define HD 64
#define WIN 512
#define DMODEL 1024

// async 16B global -> LDS (wave-uniform LDS base + lane*16 semantics)
#define GLOAD16(g, l)                                                        \
    __builtin_amdgcn_global_load_lds(                                        \
        (const __attribute__((address_space(1))) unsigned int*)(g),          \
        (__attribute__((address_space(3))) unsigned int*)(l), 16, 0, 0)

// ---------------- cast X (fp32 -> bf16), vectorized ----------------
__global__ void cast_bf16_kernel(const float* __restrict__ X,
                                 __hip_bfloat16* __restrict__ Y, int n) {
    int i = (blockIdx.x * 256 + threadIdx.x) * 4;
    if (i + 3 < n) {
        float4 v = *reinterpret_cast<const float4*>(X + i);
        Y[i + 0] = __float2bfloat16(v.x);
        Y[i + 1] = __float2bfloat16(v.y);
        Y[i + 2] = __float2bfloat16(v.z);
        Y[i + 3] = __float2bfloat16(v.w);
    }
}

// ---------------- transpose + cast: W[K][N] fp32 -> WT[N][K] bf16 ----------------
__global__ void transpose_cast_kernel(const float* __restrict__ W,
                                      __hip_bfloat16* __restrict__ WT,
                                      int K, int N) {
    __shared__ float tile[32][33];
    int nx = blockIdx.x * 32 + threadIdx.x;
    int k0 = blockIdx.y * 32;
#pragma unroll
    for (int r = 0; r < 4; ++r) {
        int k = k0 + threadIdx.y + r * 8;
        tile[threadIdx.y + r * 8][threadIdx.x] = W[(size_t)k * N + nx];
    }
    __syncthreads();
#pragma unroll
    for (int r = 0; r < 4; ++r) {
        int nn = blockIdx.x * 32 + threadIdx.y + r * 8;
        int kk = k0 + threadIdx.x;
        WT[(size_t)nn * K + kk] = __float2bfloat16(tile[threadIdx.x][threadIdx.y + r * 8]);
    }
}

// ---------------- m97-style GEMM: 64(M)x128(N) tile, 128 thr = 2 waves ----------
// wave tile 64x64 (4x4 MFMA 16x16x32) -> 16 MFMA : 8 ds_read_b128 per iter.
// global_load_lds width-16 staging, BK=32, LDS unpadded (lane-contiguity req).
// MODE 0: fused QKV epilogue (cols 0-1023 -> Qb bf16, 1024-1535 -> Kb bf16,
//         1536-2047 -> VT transposed bf16). MODE 1: fp32 C (row stride N).
template <int MODE>
__global__ __launch_bounds__(128) void gemm128_kernel(
    const __hip_bfloat16* __restrict__ A,
    const __hip_bfloat16* __restrict__ BT,
    void* __restrict__ o0, void* __restrict__ o1, void* __restrict__ o2,
    int N, int K) {
    __shared__ __hip_bfloat16 ldsA[64 * 32];    // 4 KB
    __shared__ __hip_bfloat16 ldsB[128 * 32];   // 8 KB
    const int tx = threadIdx.x;
    const int wave = tx >> 6;
    const int lane = tx & 63;
    const int l16 = lane & 15;
    const int quad = lane >> 4;
    const int col0 = blockIdx.x * 128;
    const int row0 = blockIdx.y * 64;
    const int wcol = wave * 64;

    f32x4 acc[4][4] = {};

    // staging: A = 256 chunks of 16B (2/thread), B = 512 chunks (4/thread)
    const int arow = tx >> 2;            // 0..31
    const int kc8 = (tx & 3) * 8;        // element offset within BK row
    const __hip_bfloat16* gA = A + (size_t)(row0 + arow) * K + kc8;
    const __hip_bfloat16* gB = BT + (size_t)(col0 + arow) * K + kc8;
    char* lA = (char*)ldsA + tx * 16;
    char* lB = (char*)ldsB + tx * 16;

    for (int k0 = 0; k0 < K; k0 += 32) {
        GLOAD16(gA + k0, lA);
        GLOAD16(gA + (size_t)32 * K + k0, lA + 2048);
#pragma unroll
        for (int r = 0; r < 4; ++r)
            GLOAD16(gB + (size_t)r * 32 * K + k0, lB + r * 2048);
        __syncthreads();
        short8 af[4], bf[4];
#pragma unroll
        for (int i = 0; i < 4; ++i) {
            af[i] = *reinterpret_cast<const short8*>(ldsA + (i * 16 + l16) * 32 + quad * 8);
            bf[i] = *reinterpret_cast<const short8*>(ldsB + (wcol + i * 16 + l16) * 32 + quad * 8);
        }
#pragma unroll
        for (int mi = 0; mi < 4; ++mi)
#pragma unroll
            for (int ni = 0; ni < 4; ++ni)
                acc[mi][ni] = __builtin_amdgcn_mfma_f32_16x16x32_bf16(
                    af[mi], bf[ni], acc[mi][ni], 0, 0, 0);
        __syncthreads();
    }

    if (MODE == 0) {
        if (col0 < DMODEL) {                       // Q region -> bf16 [row][1024]
            __hip_bfloat16* Qo = (__hip_bfloat16*)o0;
#pragma unroll
            for (int mi = 0; mi < 4; ++mi)
#pragma unroll
                for (int ni = 0; ni < 4; ++ni) {
                    size_t col = col0 + wcol + ni * 16 + l16;
#pragma unroll
                    for (int r = 0; r < 4; ++r)
                        Qo[(size_t)(row0 + mi * 16 + quad * 4 + r) * (NH * HD) + col] =
                            __float2bfloat16(acc[mi][ni][r]);
                }
        } else if (col0 < DMODEL + 512) {          // K region -> bf16 [row][512]
            __hip_bfloat16* Ko = (__hip_bfloat16*)o1;
#pragma unroll
            for (int mi = 0; mi < 4; ++mi)
#pragma unroll
                for (int ni = 0; ni < 4; ++ni) {
                    size_t col = col0 - DMODEL + wcol + ni * 16 + l16;
#pragma unroll
                    for (int r = 0; r < 4; ++r)
                        Ko[(size_t)(row0 + mi * 16 + quad * 4 + r) * (NKV * HD) + col] =
                            __float2bfloat16(acc[mi][ni][r]);
                }
        } else {                                   // V region -> transposed VT
            __hip_bfloat16* VTo = (__hip_bfloat16*)o2;
            int bb = row0 >> 11;
#pragma unroll
            for (int mi = 0; mi < 4; ++mi) {
                int s = ((row0 + mi * 16 + quad * 4) & (S_LEN - 1));
#pragma unroll
                for (int ni = 0; ni < 4; ++ni) {
                    int colv = col0 - 1536 + wcol + ni * 16 + l16;   // 0..511
                    int vh = colv >> 6, d = colv & 63;
                    alignas(8) __hip_bfloat16 hv[4];
#pragma unroll
                    for (int r = 0; r < 4; ++r) hv[r] = __float2bfloat16(acc[mi][ni][r]);
                    *reinterpret_cast<ushort4*>(
                        VTo + ((size_t)(bb * NKV + vh) * HD + d) * S_LEN + s) =
                        *reinterpret_cast<ushort4*>(hv);
                }
            }
        }
    } else {                                       // fp32 C
        float* Co = (float*)o0;
#pragma unroll
        for (int mi = 0; mi < 4; ++mi)
#pragma unroll
            for (int ni = 0; ni < 4; ++ni) {
                size_t col = col0 + wcol + ni * 16 + l16;
#pragma unroll
                for (int r = 0; r < 4; ++r)
                    Co[(size_t)(row0 + mi * 16 + quad * 4 + r) * N + col] = acc[mi][ni][r];
            }
    }
}

// ---------------- RoPE in-place on bf16 buffer [rows][nheads*64] ----------------
__global__ void rope_bf16_kernel(__hip_bfloat16* __restrict__ X, int nheads) {
    int idx = blockIdx.x * 256 + threadIdx.x;
    int d = idx & 31;
    int hh = (idx >> 5) % nheads;
    int row = idx / (32 * nheads);
    int pos = row & (S_LEN - 1);
    size_t base = (size_t)row * (nheads * 64) + hh * 64 + d;
    float x1 = __bfloat162float(X[base]);
    float x2 = __bfloat162float(X[base + 32]);
    float inv_freq = exp2f(-(float)d * (13.287712379549449f / 32.0f));
    float ang = (float)pos * inv_freq;
    float c = cosf(ang), s = sinf(ang);
    X[base]      = __float2bfloat16(x1 * c - x2 * s);
    X[base + 32] = __float2bfloat16(x2 * c + x1 * s);
}

// ---------------- MFMA flash attention (S^T formulation) ----------------
// grid (S/64, NH, B), 256 thr = 4 waves; wave w: queries q0+16w+l16 (1/lane).
// S^T = K@Q^T -> C layout col=query,row=key: softmax = in-lane reduce over 16
// scores + 2 shfl_xor; P^T written as packed b64; O^T = VT@P^T; mask only on
// diagonal + trailing chunks (wave-uniform branch).
__global__ __launch_bounds__(256) void attn_mfma_kernel(
    const __hip_bfloat16* __restrict__ Q,
    const __hip_bfloat16* __restrict__ K,
    const __hip_bfloat16* __restrict__ VT,
    __hip_bfloat16* __restrict__ O) {
    __shared__ __hip_bfloat16 ldsK[64][80];
    __shared__ __hip_bfloat16 ldsVT[64][80];
    __shared__ __hip_bfloat16 ldsP[4][16][80];
    const int tx = threadIdx.x;
    const int wave = tx >> 6;
    const int lane = tx & 63;
    const int l16 = lane & 15;
    const int quad = lane >> 4;
    const int q0 = blockIdx.x * 64;
    const int h = blockIdx.y;
    const int b = blockIdx.z;
    const int kvh = h >> 1;
    const int qi = q0 + wave * 16 + l16;     // this lane's query

    short8 aq0, aq1;                          // Q B-frag (n=query, k=d)
    {
        const __hip_bfloat16* qp =
            Q + (size_t)(b * S_LEN + qi) * (NH * HD) + h * HD + quad * 8;
        aq0 = *reinterpret_cast<const short8*>(qp);
        aq1 = *reinterpret_cast<const short8*>(qp + 32);
    }
    f32x4 acc_o[4] = {};
    float m = -1e30f, l = 0.f;

    const int kstart = (q0 >= WIN) ? (q0 - WIN) : 0;
    for (int j0 = kstart; j0 <= q0; j0 += 64) {
        // stage K[key][d], VT[d][key]
#pragma unroll
        for (int r = 0; r < 2; ++r) {
            int f = tx + r * 256;
            int a = f >> 3, e8 = f & 7;
            *reinterpret_cast<uint4*>(&ldsK[a][e8 * 8]) =
                *reinterpret_cast<const uint4*>(
                    K + (size_t)(b * S_LEN + j0 + a) * (NKV * HD) + kvh * HD + e8 * 8);
            *reinterpret_cast<uint4*>(&ldsVT[a][e8 * 8]) =
                *reinterpret_cast<const uint4*>(
                    VT + ((size_t)(b * NKV + kvh) * HD + a) * S_LEN + j0 + e8 * 8);
        }
        __syncthreads();

        // S^T = K @ Q^T : rows = keys, cols = queries
        f32x4 sacc[4] = {};
#pragma unroll
        for (int t = 0; t < 4; ++t) {
            short8 bk0 = *reinterpret_cast<const short8*>(&ldsK[t * 16 + l16][quad * 8]);
            short8 bk1 = *reinterpret_cast<const short8*>(&ldsK[t * 16 + l16][32 + quad * 8]);
            sacc[t] = __builtin_amdgcn_mfma_f32_16x16x32_bf16(bk0, aq0, sacc[t], 0, 0, 0);
            sacc[t] = __builtin_amdgcn_mfma_f32_16x16x32_bf16(bk1, aq1, sacc[t], 0, 0, 0);
        }

        // scale (+ mask only on diagonal / trailing chunk)
        float sv[4][4];
        const bool need_mask = (j0 == q0) || (q0 >= WIN && j0 == kstart);
        if (need_mask) {
#pragma unroll
            for (int t = 0; t < 4; ++t)
#pragma unroll
                for (int r = 0; r < 4; ++r) {
                    int j = j0 + t * 16 + quad * 4 + r;
                    bool ok = (j <= qi) && (j + WIN >= qi);
                    sv[t][r] = ok ? sacc[t][r] * 0.125f : -1e30f;
                }
        } else {
#pragma unroll
            for (int t = 0; t < 4; ++t)
#pragma unroll
                for (int r = 0; r < 4; ++r) sv[t][r] = sacc[t][r] * 0.125f;
        }

        // online softmax: in-lane reduce 16 scores + 2 shuffles (quads)
        float cm = -1e30f;
#pragma unroll
        for (int t = 0; t < 4; ++t)
#pragma unroll
            for (int r = 0; r < 4; ++r) cm = fmaxf(cm, sv[t][r]);
        cm = fmaxf(cm, __shfl_xor(cm, 16));
        cm = fmaxf(cm, __shfl_xor(cm, 32));
        float mn = fmaxf(m, cm);
        float alpha = __expf(m - mn);
        m = mn;
        float sp = 0.f;
#pragma unroll
        for (int t = 0; t < 4; ++t)
#pragma unroll
            for (int r = 0; r < 4; ++r) { sv[t][r] = __expf(sv[t][r] - mn); sp += sv[t][r]; }
        sp += __shfl_xor(sp, 16);
        sp += __shfl_xor(sp, 32);
        l = l * alpha + sp;
#pragma unroll
        for (int t = 0; t < 4; ++t)
#pragma unroll
            for (int r = 0; r < 4; ++r) acc_o[t][r] *= alpha;

        // P^T -> LDS, packed 4 consecutive keys per write (b64)
#pragma unroll
        for (int t = 0; t < 4; ++t) {
            alignas(8) __hip_bfloat16 hp[4];
#pragma unroll
            for (int r = 0; r < 4; ++r) hp[r] = __float2bfloat16(sv[t][r]);
            *reinterpret_cast<ushort4*>(&ldsP[wave][l16][t * 16 + quad * 4]) =
                *reinterpret_cast<ushort4*>(hp);
        }

        // O^T += VT @ P^T  (same-wave LDS write->read, in order)
#pragma unroll
        for (int ks = 0; ks < 2; ++ks) {
            short8 pf = *reinterpret_cast<const short8*>(&ldsP[wave][l16][ks * 32 + quad * 8]);
#pragma unroll
            for (int t = 0; t < 4; ++t) {
                short8 vf = *reinterpret_cast<const short8*>(
                    &ldsVT[t * 16 + l16][ks * 32 + quad * 8]);
                acc_o[t] = __builtin_amdgcn_mfma_f32_16x16x32_bf16(vf, pf, acc_o[t], 0, 0, 0);
            }
        }
        __syncthreads();
    }

    // O^T[d][q]: lane holds d = t*16 + quad*4 + r for its query qi
    float inv = 1.f / l;
    __hip_bfloat16* op = O + (size_t)(b * S_LEN + qi) * (NH * HD) + h * HD;
#pragma unroll
    for (int t = 0; t < 4; ++t) {
        alignas(8) __hip_bfloat16 ho[4];
#pragma unroll
        for (int r = 0; r < 4; ++r) ho[r] = __float2bfloat16(acc_o[t][r] * inv);
        *reinterpret_cast<ushort4*>(op + t * 16 + quad * 4) =
            *reinterpret_cast<ushort4*>(ho);
    }
}

// ---------------- launch ----------------
extern "C" void kernel_launch(void* const* d_in, const int* in_sizes, int n_in,
                              void* d_out, int out_size, void* d_ws, size_t ws_size,
                              hipStream_t stream) {
    const float* X  = (const float*)d_in[0];
    const float* Wq = (const float*)d_in[1];
    const float* Wk = (const float*)d_in[2];
    const float* Wv = (const float*)d_in[3];
    const float* Wo = (const float*)d_in[4];
    float* out = (float*)d_out;

    const int ROWS = 2 * S_LEN;               // 4096
    char* ws = (char*)d_ws;
    size_t off = 0;
    __hip_bfloat16* Xb     = (__hip_bfloat16*)(ws + off); off += (size_t)ROWS * DMODEL * 2;      // 8 MB
    __hip_bfloat16* WqkvT  = (__hip_bfloat16*)(ws + off); off += (size_t)2048 * DMODEL * 2;      // 4 MB
    __hip_bfloat16* WoT    = (__hip_bfloat16*)(ws + off); off += (size_t)DMODEL * DMODEL * 2;    // 2 MB
    __hip_bfloat16* Qb     = (__hip_bfloat16*)(ws + off); off += (size_t)ROWS * (NH * HD) * 2;   // 8 MB
    __hip_bfloat16* Kb     = (__hip_bfloat16*)(ws + off); off += (size_t)ROWS * (NKV * HD) * 2;  // 4 MB
    __hip_bfloat16* VTg    = (__hip_bfloat16*)(ws + off); off += (size_t)ROWS * (NKV * HD) * 2;  // 4 MB
    __hip_bfloat16* Ob     = (__hip_bfloat16*)(ws + off); off += (size_t)ROWS * (NH * HD) * 2;   // 8 MB

    // 1. casts / transposes (BT rows: [Wq^T ; Wk^T ; Wv^T])
    cast_bf16_kernel<<<(ROWS * DMODEL) / (256 * 4), 256, 0, stream>>>(X, Xb, ROWS * DMODEL);
    transpose_cast_kernel<<<dim3(DMODEL / 32, DMODEL / 32), dim3(32, 8), 0, stream>>>(
        Wq, WqkvT, DMODEL, DMODEL);
    transpose_cast_kernel<<<dim3(512 / 32, DMODEL / 32), dim3(32, 8), 0, stream>>>(
        Wk, WqkvT + (size_t)1024 * DMODEL, DMODEL, 512);
    transpose_cast_kernel<<<dim3(512 / 32, DMODEL / 32), dim3(32, 8), 0, stream>>>(
        Wv, WqkvT + (size_t)1536 * DMODEL, DMODEL, 512);
    transpose_cast_kernel<<<dim3(DMODEL / 32, DMODEL / 32), dim3(32, 8), 0, stream>>>(
        Wo, WoT, DMODEL, DMODEL);

    // 2. fused QKV projection (N=2048): Q,K bf16; V transposed
    gemm128_kernel<0><<<dim3(2048 / 128, ROWS / 64), 128, 0, stream>>>(
        Xb, WqkvT, Qb, Kb, VTg, 2048, DMODEL);

    // 3. RoPE in-place (bf16)
    rope_bf16_kernel<<<(ROWS * NH * 32) / 256, 256, 0, stream>>>(Qb, NH);
    rope_bf16_kernel<<<(ROWS * NKV * 32) / 256, 256, 0, stream>>>(Kb, NKV);

    // 4. MFMA flash attention (S^T)
    attn_mfma_kernel<<<dim3(S_LEN / 64, NH, 2), 256, 0, stream>>>(Qb, Kb, VTg, Ob);

    // 5. output projection -> fp32
    gemm128_kernel<1><<<dim3(DMODEL / 128, ROWS / 64), 128, 0, stream>>>(
        Ob, WoT, out, nullptr, nullptr, DMODEL, DMODEL);
}